// Round 4
// baseline (39.381 us; speedup 1.0000x reference)
//
#include <hip/hip_runtime.h>
#include <math.h>

// x: (8, 12, 4096, 64) f32. Group = (b, t): 768 elements x[b, h, t, c].
// out[b,h,t,c] = delta * 2^-clip(rint(-log2(max(x/delta,1e-8))),0,255), delta = group max.
//
// Structure: ONE WAVE per (b,t) group. 64 lanes x 3 float4 = 768 elements.
// No LDS, no __syncthreads -- max reduction is 6x shfl_xor within the wave.
// 256-thread blocks = 4 independent groups/block; grid = 32768/4 = 8192.

#define BB 8
#define HH 12
#define TT 4096
#define CC 64
#define HSTRIDE ((size_t)TT * CC)   // stride between h planes, in floats

// native vector type: __builtin_nontemporal_* requires scalar/ext-vector, not HIP_vector_type
typedef float vf4 __attribute__((ext_vector_type(4)));

__global__ __launch_bounds__(256) void log2q_kernel(const float* __restrict__ x,
                                                    float* __restrict__ out) {
    const int wave = threadIdx.x >> 6;
    const int lane = threadIdx.x & 63;
    const int g    = (blockIdx.x << 2) | wave;   // group id 0..32767
    const int b    = g >> 12;
    const int t    = g & 4095;

    const int hh = lane >> 4;          // 0..3 (h sub-block)
    const int c4 = (lane & 15) << 2;   // 0,4,...,60
    const size_t base = (size_t)b * (HH * HSTRIDE) + (size_t)t * CC + c4;

    // ---- 3 x 16B nontemporal loads (12 h-rows covered in 3 iterations) ----
    vf4 v[3];
#pragma unroll
    for (int k = 0; k < 3; ++k) {
        const vf4* p = reinterpret_cast<const vf4*>(x + base + (size_t)(k * 4 + hh) * HSTRIDE);
        v[k] = __builtin_nontemporal_load(p);
    }

    // ---- exact group max: 11-op lane tree + 6x shfl_xor, no LDS ----
    float m = fmaxf(fmaxf(fmaxf(v[0].x, v[0].y), fmaxf(v[0].z, v[0].w)),
             fmaxf(fmaxf(fmaxf(v[1].x, v[1].y), fmaxf(v[1].z, v[1].w)),
                   fmaxf(fmaxf(v[2].x, v[2].y), fmaxf(v[2].z, v[2].w))));
#pragma unroll
    for (int off = 32; off > 0; off >>= 1)
        m = fmaxf(m, __shfl_xor(m, off));
    const float delta = m;

#pragma unroll
    for (int k = 0; k < 3; ++k) {
        float r[4] = {v[k].x, v[k].y, v[k].z, v[k].w};
        float o[4];
#pragma unroll
        for (int j = 0; j < 4; ++j) {
            // IEEE f32 division to match jnp's lax.div bit-exactly
            const float ratio = fmaxf(r[j] / delta, 1e-8f);

            // fast path: hardware v_log_f32
            const float nv = -__log2f(ratio);
            float xi = rintf(nv);
            const float d = fabsf(nv - xi);
            if (0.5f - d < 1e-4f) {
                // near a half-integer cliff: replicate jnp.log2 = log(x)/log(2)
                // with a correctly-rounded f32 log, then IEEE f32 divide, then
                // round-half-even (matches jnp.round).
                const float tt = (float)log((double)ratio);
                const float v2 = tt / 0x1.62e43p-1f;  // fl32(ln 2)
                xi = rintf(-v2);
            }
            // x_quant = clip(x_int/255, 0, 1) * 255  (replicated with IEEE ops)
            const float q = fminf(fmaxf(xi / 255.0f, 0.0f), 1.0f) * 255.0f;
            const float p = exp2f(-q);   // exact for integer q
            o[j] = (xi >= 256.0f) ? 0.0f : delta * p;
        }
        vf4 ov = {o[0], o[1], o[2], o[3]};
        vf4* po = reinterpret_cast<vf4*>(out + base + (size_t)(k * 4 + hh) * HSTRIDE);
        __builtin_nontemporal_store(ov, po);
    }
}

extern "C" void kernel_launch(void* const* d_in, const int* in_sizes, int n_in,
                              void* d_out, int out_size, void* d_ws, size_t ws_size,
                              hipStream_t stream) {
    const float* x = (const float*)d_in[0];
    float* out = (float*)d_out;
    dim3 grid((BB * TT) / 4);   // 8192 blocks, 4 wave-groups each
    dim3 block(256);
    log2q_kernel<<<grid, block, 0, stream>>>(x, out);
}

// Round 5
// 37.190 us; speedup vs baseline: 1.0589x; 1.0589x over previous
//
#include <hip/hip_runtime.h>
#include <math.h>

// x: (8, 12, 4096, 64) f32. Group = (b, t): 768 elements x[b, h, t, c].
// out = delta * 2^-rint(-log2(max(x/delta,1e-8))), delta = group max.
// (ref's clip(xi/255)*255 round-trip and >=256 mask are no-ops for ratio>=1e-8:
//  xi in [0,27]; round-trip deviation <=1ulp -> rel err <=1.2e-6, << absmax budget.)
//
// Structure: ONE WAVE per (b,t) group. 64 lanes x 3 vf4 = 768 elements.
// Fast path: v_rcp + v_log_f32; elements within 1e-4 of a half-integer cliff
// (~0.02%) recompute via IEEE f32 div + correctly-rounded log -> matches ref.

#define BB 8
#define HH 12
#define TT 4096
#define CC 64
#define HSTRIDE ((size_t)TT * CC)   // stride between h planes, in floats

typedef float vf4 __attribute__((ext_vector_type(4)));

__global__ __launch_bounds__(256) void log2q_kernel(const float* __restrict__ x,
                                                    float* __restrict__ out) {
    const int wave = threadIdx.x >> 6;
    const int lane = threadIdx.x & 63;
    const int g    = (blockIdx.x << 2) | wave;   // group id 0..32767
    const int b    = g >> 12;
    const int t    = g & 4095;

    const int hh = lane >> 4;          // 0..3 (h sub-block)
    const int c4 = (lane & 15) << 2;   // 0,4,...,60
    const size_t base = (size_t)b * (HH * HSTRIDE) + (size_t)t * CC + c4;

    // ---- 3 x 16B nontemporal loads (12 h-rows in 3 iterations) ----
    vf4 v[3];
#pragma unroll
    for (int k = 0; k < 3; ++k) {
        const vf4* p = reinterpret_cast<const vf4*>(x + base + (size_t)(k * 4 + hh) * HSTRIDE);
        v[k] = __builtin_nontemporal_load(p);
    }

    // ---- exact group max: lane tree + 6x shfl_xor, no LDS ----
    float m = fmaxf(fmaxf(fmaxf(v[0].x, v[0].y), fmaxf(v[0].z, v[0].w)),
             fmaxf(fmaxf(fmaxf(v[1].x, v[1].y), fmaxf(v[1].z, v[1].w)),
                   fmaxf(fmaxf(v[2].x, v[2].y), fmaxf(v[2].z, v[2].w))));
#pragma unroll
    for (int off = 32; off > 0; off >>= 1)
        m = fmaxf(m, __shfl_xor(m, off));
    const float delta = m;
    const float rdelta = __builtin_amdgcn_rcpf(delta);   // fast-path reciprocal
    const int   dbits  = __float_as_int(delta);

#pragma unroll
    for (int k = 0; k < 3; ++k) {
        float r[4] = {v[k].x, v[k].y, v[k].z, v[k].w};
        float o[4];
#pragma unroll
        for (int j = 0; j < 4; ++j) {
            // fast ratio: rcp+mul (log2-space err ~3e-6, << 1e-4 guard window)
            const float rf = fmaxf(r[j] * rdelta, 1e-8f);
            const float nv = -__log2f(rf);
            float xi = rintf(nv);
            if (0.5f - fabsf(nv - xi) < 1e-4f) {
                // near a half-integer cliff: exact recompute matching ref chain
                const float ratio = fmaxf(r[j] / delta, 1e-8f);  // IEEE f32 div
                const float tt = (float)log((double)ratio);
                const float v2 = tt / 0x1.62e43p-1f;             // fl32(ln 2)
                xi = rintf(-v2);
            }
            // out = delta * 2^-k exactly, via exponent decrement (k in [0,27],
            // delta ~1 so result stays normal)
            const int kq = (int)xi;
            o[j] = __int_as_float(dbits - (kq << 23));
        }
        vf4 ov = {o[0], o[1], o[2], o[3]};
        vf4* po = reinterpret_cast<vf4*>(out + base + (size_t)(k * 4 + hh) * HSTRIDE);
        __builtin_nontemporal_store(ov, po);
    }
}

extern "C" void kernel_launch(void* const* d_in, const int* in_sizes, int n_in,
                              void* d_out, int out_size, void* d_ws, size_t ws_size,
                              hipStream_t stream) {
    const float* x = (const float*)d_in[0];
    float* out = (float*)d_out;
    dim3 grid((BB * TT) / 4);   // 8192 blocks, 4 wave-groups each
    dim3 block(256);
    log2q_kernel<<<grid, block, 0, stream>>>(x, out);
}